// Round 1
// baseline (124127.734 us; speedup 1.0000x reference)
//
#include <hip/hip_runtime.h>
#include <hip/hip_fp16.h>

#define BB 128
#define II 64
#define SS 2048
#define HH 128
#define GG 512   // 4*H
#define OO 64

__device__ __forceinline__ float sigm(float v) {
    return __builtin_amdgcn_rcpf(1.0f + __expf(-v));
}
__device__ __forceinline__ float tanh_f(float v) {
    float a = fabsf(v);
    float e = __expf(-2.0f * a);                      // in (0,1], no overflow
    float r = (1.0f - e) * __builtin_amdgcn_rcpf(1.0f + e);
    return v < 0.0f ? -r : r;
}

// One workgroup per batch element. 512 threads: thread j owns outer-gate
// column j and inner-gate column j. Weights live in registers as fp16
// (224 VGPRs/thread) -> no weight traffic inside the 2048-step scan.
__global__ __launch_bounds__(512, 2) void nlstm_scan(
    const float* __restrict__ x,
    const float* __restrict__ Wx_out, const float* __restrict__ Wh_out,
    const float* __restrict__ b_out,
    const float* __restrict__ Wx_in, const float* __restrict__ Wh_in,
    const float* __restrict__ b_in,
    const float* __restrict__ W_lin, const float* __restrict__ b_lin,
    float* __restrict__ out)
{
    const int b = blockIdx.x;
    const int j = threadIdx.x;

    __shared__ __align__(16) float xbuf[II];
    __shared__ __align__(16) float hbuf[HH];
    __shared__ __align__(16) float cbuf[HH];
    __shared__ __align__(16) float cnbuf[HH];
    __shared__ __align__(16) float xibuf[HH];
    __shared__ __align__(16) float hibuf[HH];
    __shared__ __align__(16) float actO[GG];
    __shared__ __align__(16) float actI[GG];
    __shared__ __align__(16) float wlds[OO * (HH + 4)];  // W_lin, padded stride

    // ---- register-resident fp16 weights (column j of each matrix) ----
    __half2 wxo[II / 2];   // 32 VGPRs
    __half2 who[HH / 2];   // 64
    __half2 wxi[HH / 2];   // 64
    __half2 whi[HH / 2];   // 64
#pragma unroll
    for (int p = 0; p < II / 2; ++p)
        wxo[p] = __floats2half2_rn(Wx_out[(2 * p) * GG + j], Wx_out[(2 * p + 1) * GG + j]);
#pragma unroll
    for (int p = 0; p < HH / 2; ++p)
        who[p] = __floats2half2_rn(Wh_out[(2 * p) * GG + j], Wh_out[(2 * p + 1) * GG + j]);
#pragma unroll
    for (int p = 0; p < HH / 2; ++p)
        wxi[p] = __floats2half2_rn(Wx_in[(2 * p) * GG + j], Wx_in[(2 * p + 1) * GG + j]);
#pragma unroll
    for (int p = 0; p < HH / 2; ++p)
        whi[p] = __floats2half2_rn(Wh_in[(2 * p) * GG + j], Wh_in[(2 * p + 1) * GG + j]);

    const float bo = b_out[j];
    const float bi = b_in[j];
    const int   pn = j >> 3;   // projection output column (0..63)
    const int   ps = j & 7;    // projection k-slice (0..7)
    const float bl = b_lin[pn];

    // W_lin (O x H fp32) -> LDS with padded row stride to spread banks
#pragma unroll
    for (int q = 0; q < (OO * HH) / 512; ++q) {
        const int l = q * 512 + j;
        wlds[(l >> 7) * (HH + 4) + (l & (HH - 1))] = W_lin[l];
    }

    if (j < HH) { hbuf[j] = 0.f; cbuf[j] = 0.f; cnbuf[j] = 0.f; }
    __syncthreads();

    const float* xrow = x + (size_t)b * II * SS;   // x[b,i,t] = xrow[i*SS+t]
    float* orow = out + (size_t)b * SS * OO;

#pragma unroll 1
    for (int t = 0; t < SS; ++t) {
        if (j < II) xbuf[j] = xrow[j * SS + t];
        __syncthreads();   // B1: xt staged, h from prev step stable

        // ---- outer gates: col j of  xt@Wx_out + h@Wh_out + b_out ----
        float acc = bo;
#pragma unroll
        for (int k4 = 0; k4 < II / 4; ++k4) {
            const float4 xv = reinterpret_cast<const float4*>(xbuf)[k4];
            const __half2 w0 = wxo[2 * k4], w1 = wxo[2 * k4 + 1];
            acc = fmaf(__low2float(w0),  xv.x, acc);
            acc = fmaf(__high2float(w0), xv.y, acc);
            acc = fmaf(__low2float(w1),  xv.z, acc);
            acc = fmaf(__high2float(w1), xv.w, acc);
        }
#pragma unroll
        for (int k4 = 0; k4 < HH / 4; ++k4) {
            const float4 hv = reinterpret_cast<const float4*>(hbuf)[k4];
            const __half2 w0 = who[2 * k4], w1 = who[2 * k4 + 1];
            acc = fmaf(__low2float(w0),  hv.x, acc);
            acc = fmaf(__high2float(w0), hv.y, acc);
            acc = fmaf(__low2float(w1),  hv.z, acc);
            acc = fmaf(__high2float(w1), hv.w, acc);
        }
        // blocks: i=[0,128) f=[128,256) o=[256,384) sigmoid; g=[384,512) tanh
        actO[j] = (j < 384) ? sigm(acc) : tanh_f(acc);   // wave-uniform branch
        __syncthreads();   // B2

        if (j < HH) {
            xibuf[j] = actO[j] * actO[384 + j];          // x_in = sig(i)*tanh(g)
        } else if (j < 2 * HH) {
            const int m = j - HH;
            hibuf[m] = actO[j] * cbuf[m];                // h_in = sig(f)*c
        }
        __syncthreads();   // B3

        // ---- inner gates: col j of  x_in@Wx_in + h_in@Wh_in + b_in ----
        float acc2 = bi;
#pragma unroll
        for (int k4 = 0; k4 < HH / 4; ++k4) {
            const float4 xv = reinterpret_cast<const float4*>(xibuf)[k4];
            const __half2 w0 = wxi[2 * k4], w1 = wxi[2 * k4 + 1];
            acc2 = fmaf(__low2float(w0),  xv.x, acc2);
            acc2 = fmaf(__high2float(w0), xv.y, acc2);
            acc2 = fmaf(__low2float(w1),  xv.z, acc2);
            acc2 = fmaf(__high2float(w1), xv.w, acc2);
        }
#pragma unroll
        for (int k4 = 0; k4 < HH / 4; ++k4) {
            const float4 hv = reinterpret_cast<const float4*>(hibuf)[k4];
            const __half2 w0 = whi[2 * k4], w1 = whi[2 * k4 + 1];
            acc2 = fmaf(__low2float(w0),  hv.x, acc2);
            acc2 = fmaf(__high2float(w0), hv.y, acc2);
            acc2 = fmaf(__low2float(w1),  hv.z, acc2);
            acc2 = fmaf(__high2float(w1), hv.w, acc2);
        }
        actI[j] = (j < 384) ? sigm(acc2) : tanh_f(acc2);
        __syncthreads();   // B4

        // ---- state update (threads 0..127, one h-dim each) ----
        if (j < HH) {
            const float cn_new = actI[HH + j] * cnbuf[j] + actI[j] * actI[384 + j];
            const float c_new  = actI[2 * HH + j] * tanh_f(cn_new);
            const float h_new  = actO[2 * HH + j] * tanh_f(c_new);
            cnbuf[j] = cn_new;
            cbuf[j]  = c_new;
            hbuf[j]  = h_new;
        }
        __syncthreads();   // B5

        // ---- fused projection: out[b,t,n] = h_new @ W_lin[n,:] + b_lin ----
        float p = 0.f;
#pragma unroll
        for (int kk = 0; kk < 4; ++kk) {
            const float4 hv = reinterpret_cast<const float4*>(hbuf)[ps * 4 + kk];
            const float4 wv = *reinterpret_cast<const float4*>(
                &wlds[pn * (HH + 4) + ps * 16 + kk * 4]);
            p = fmaf(wv.x, hv.x, p);
            p = fmaf(wv.y, hv.y, p);
            p = fmaf(wv.z, hv.z, p);
            p = fmaf(wv.w, hv.w, p);
        }
        p += __shfl_down(p, 4, 8);
        p += __shfl_down(p, 2, 8);
        p += __shfl_down(p, 1, 8);
        if (ps == 0) orow[t * OO + pn] = p + bl;
    }
}

extern "C" void kernel_launch(void* const* d_in, const int* in_sizes, int n_in,
                              void* d_out, int out_size, void* d_ws, size_t ws_size,
                              hipStream_t stream) {
    (void)in_sizes; (void)n_in; (void)d_ws; (void)ws_size; (void)out_size;
    const float* x      = (const float*)d_in[0];
    const float* Wx_out = (const float*)d_in[1];
    const float* Wh_out = (const float*)d_in[2];
    const float* b_out  = (const float*)d_in[3];
    const float* Wx_in  = (const float*)d_in[4];
    const float* Wh_in  = (const float*)d_in[5];
    const float* b_in   = (const float*)d_in[6];
    const float* W_lin  = (const float*)d_in[7];
    const float* b_lin  = (const float*)d_in[8];
    float* out = (float*)d_out;

    nlstm_scan<<<dim3(BB), dim3(512), 0, stream>>>(
        x, Wx_out, Wh_out, b_out, Wx_in, Wh_in, b_in, W_lin, b_lin, out);
}

// Round 2
// 4761.213 us; speedup vs baseline: 26.0706x; 26.0706x over previous
//
#include <hip/hip_runtime.h>
#include <hip/hip_fp16.h>

#define BB 128
#define II 64
#define SS 2048
#define HH 128
#define GG 512   // 4*H
#define OO 64

typedef _Float16 f16x2 __attribute__((ext_vector_type(2)));
union F4H { float4 f4; f16x2 h[4]; };

__device__ __forceinline__ f16x2 pack2(float a, float b) {
    f16x2 r; r.x = (_Float16)a; r.y = (_Float16)b; return r;
}

__device__ __forceinline__ float dot2(f16x2 w, f16x2 v, float c) {
#if __has_builtin(__builtin_amdgcn_fdot2)
    return __builtin_amdgcn_fdot2(w, v, c, false);
#else
    return fmaf((float)w.x, (float)v.x, fmaf((float)w.y, (float)v.y, c));
#endif
}

__device__ __forceinline__ float sigm(float v) {
    return __builtin_amdgcn_rcpf(1.0f + __expf(-v));
}
__device__ __forceinline__ float tanh_f(float v) {
    float a = fabsf(v);
    float e = __expf(-2.0f * a);
    float r = (1.0f - e) * __builtin_amdgcn_rcpf(1.0f + e);
    return v < 0.0f ? -r : r;
}

// One block per batch element, 512 threads, thread j owns gate column j.
// Wh_out, Wx_in, Wh_in: fp16 in registers (192 VGPRs). Wx_out, W_lin: fp16
// in LDS. amdgpu_waves_per_eu(2) -> 256-VGPR cap (launch_bounds(512,2) gave
// an effective 128 cap last round -> total spill -> 66 GB scratch traffic).
__global__ void __launch_bounds__(512)
__attribute__((amdgpu_waves_per_eu(2)))
nlstm_scan(
    const float* __restrict__ x,
    const float* __restrict__ Wx_out, const float* __restrict__ Wh_out,
    const float* __restrict__ b_out,
    const float* __restrict__ Wx_in, const float* __restrict__ Wh_in,
    const float* __restrict__ b_in,
    const float* __restrict__ W_lin, const float* __restrict__ b_lin,
    float* __restrict__ out)
{
    const int b = blockIdx.x;
    const int j = threadIdx.x;

    // Wx_out fp16, chunk-major: chunk c (k=8c..8c+8) of column j at wxf[c*512+j].
    __shared__ __align__(16) float4 wxf[8 * 512];          // 64 KB
    // W_lin fp16, chunk-major padded: chunk c (k=8c..8c+8) of row pn at wlf[c*66+pn].
    __shared__ __align__(16) float4 wlf[16 * 66];          // 16.5 KB
    __shared__ __align__(16) f16x2 xb[II / 2];             // x_t fp16
    __shared__ __align__(16) f16x2 hb[HH / 2];             // h fp16
    __shared__ __align__(16) f16x2 xib[HH / 2];            // x_in fp16
    __shared__ __align__(16) f16x2 hib[HH / 2];            // h_in fp16
    __shared__ __align__(16) float cb[HH];                 // outer cell fp32
    __shared__ __align__(16) float cnb[HH];                // inner cell fp32
    __shared__ __align__(16) float actO[GG];
    __shared__ __align__(16) float actI[GG];

    // ---- register-resident fp16 weights (column j) : 192 VGPRs ----
    f16x2 who[HH / 2];   // Wh_out col j
    f16x2 wxi[HH / 2];   // Wx_in  col j
    f16x2 whi[HH / 2];   // Wh_in  col j
#pragma unroll
    for (int m = 0; m < HH / 2; ++m)
        who[m] = pack2(Wh_out[(2 * m) * GG + j], Wh_out[(2 * m + 1) * GG + j]);
#pragma unroll
    for (int m = 0; m < HH / 2; ++m)
        wxi[m] = pack2(Wx_in[(2 * m) * GG + j], Wx_in[(2 * m + 1) * GG + j]);
#pragma unroll
    for (int m = 0; m < HH / 2; ++m)
        whi[m] = pack2(Wh_in[(2 * m) * GG + j], Wh_in[(2 * m + 1) * GG + j]);

    const float bo = b_out[j];
    const float bi = b_in[j];
    const int   pn = j >> 3;
    const int   ps = j & 7;
    const float bl = b_lin[pn];

    // Wx_out -> LDS fp16 (thread j converts its own column)
#pragma unroll
    for (int c = 0; c < 8; ++c) {
        F4H u;
#pragma unroll
        for (int q = 0; q < 4; ++q)
            u.h[q] = pack2(Wx_out[(8 * c + 2 * q) * GG + j],
                           Wx_out[(8 * c + 2 * q + 1) * GG + j]);
        wxf[c * 512 + j] = u.f4;
    }
    // W_lin -> LDS fp16 (1024 chunks, 2 per thread)
#pragma unroll
    for (int r = 0; r < 2; ++r) {
        const int m = r * 512 + j;
        const int c = m >> 6, n = m & 63;
        F4H u;
#pragma unroll
        for (int q = 0; q < 4; ++q)
            u.h[q] = pack2(W_lin[n * HH + 8 * c + 2 * q],
                           W_lin[n * HH + 8 * c + 2 * q + 1]);
        wlf[c * 66 + n] = u.f4;
    }

    if (j < HH / 2) hb[j] = pack2(0.f, 0.f);
    if (j < HH) { cb[j] = 0.f; cnb[j] = 0.f; }
    __syncthreads();

    const float* xrow = x + (size_t)b * II * SS;   // x[b,i,t] = xrow[i*SS + t]
    float* orow = out + (size_t)b * SS * OO;

    const float4* xb4 = (const float4*)xb;   // 8 chunks
    const float4* hb4 = (const float4*)hb;   // 16 chunks
    const float4* xi4 = (const float4*)xib;
    const float4* hi4 = (const float4*)hib;

#pragma unroll 1
    for (int t = 0; t < SS; ++t) {
        if (j < II / 2)
            xb[j] = pack2(xrow[(2 * j) * SS + t], xrow[(2 * j + 1) * SS + t]);
        __syncthreads();   // B1

        // ---- outer gates: col j of xt@Wx_out + h@Wh_out + b ----
        float acc = bo;
#pragma unroll
        for (int c = 0; c < 8; ++c) {
            F4H xu; xu.f4 = xb4[c];
            F4H wu; wu.f4 = wxf[c * 512 + j];
            acc = dot2(wu.h[0], xu.h[0], acc);
            acc = dot2(wu.h[1], xu.h[1], acc);
            acc = dot2(wu.h[2], xu.h[2], acc);
            acc = dot2(wu.h[3], xu.h[3], acc);
        }
#pragma unroll
        for (int c = 0; c < 16; ++c) {
            F4H hu; hu.f4 = hb4[c];
            acc = dot2(who[4 * c + 0], hu.h[0], acc);
            acc = dot2(who[4 * c + 1], hu.h[1], acc);
            acc = dot2(who[4 * c + 2], hu.h[2], acc);
            acc = dot2(who[4 * c + 3], hu.h[3], acc);
        }
        actO[j] = (j < 384) ? sigm(acc) : tanh_f(acc);
        __syncthreads();   // B2

        if (j < II) {  // j<64: x_in pairs
            xib[j] = pack2(actO[2 * j] * actO[384 + 2 * j],
                           actO[2 * j + 1] * actO[384 + 2 * j + 1]);
        } else if (j < II + HH / 2) {  // h_in pairs
            const int m = j - II;
            hib[m] = pack2(actO[128 + 2 * m] * cb[2 * m],
                           actO[128 + 2 * m + 1] * cb[2 * m + 1]);
        }
        __syncthreads();   // B3

        // ---- inner gates: col j of x_in@Wx_in + h_in@Wh_in + b ----
        float acc2 = bi;
#pragma unroll
        for (int c = 0; c < 16; ++c) {
            F4H xu; xu.f4 = xi4[c];
            acc2 = dot2(wxi[4 * c + 0], xu.h[0], acc2);
            acc2 = dot2(wxi[4 * c + 1], xu.h[1], acc2);
            acc2 = dot2(wxi[4 * c + 2], xu.h[2], acc2);
            acc2 = dot2(wxi[4 * c + 3], xu.h[3], acc2);
        }
#pragma unroll
        for (int c = 0; c < 16; ++c) {
            F4H hu; hu.f4 = hi4[c];
            acc2 = dot2(whi[4 * c + 0], hu.h[0], acc2);
            acc2 = dot2(whi[4 * c + 1], hu.h[1], acc2);
            acc2 = dot2(whi[4 * c + 2], hu.h[2], acc2);
            acc2 = dot2(whi[4 * c + 3], hu.h[3], acc2);
        }
        actI[j] = (j < 384) ? sigm(acc2) : tanh_f(acc2);
        __syncthreads();   // B4

        // ---- state update (threads 0..127) ----
        if (j < HH) {
            const float cn_new = actI[HH + j] * cnb[j] + actI[j] * actI[384 + j];
            const float c_new  = actI[2 * HH + j] * tanh_f(cn_new);
            const float h_new  = actO[2 * HH + j] * tanh_f(c_new);
            cnb[j] = cn_new;
            cb[j]  = c_new;
            ((_Float16*)hb)[j] = (_Float16)h_new;
        }
        __syncthreads();   // B5

        // ---- fused projection: out[b,t,pn] = h @ W_lin[pn,:] + b_lin ----
        float p = 0.f;
#pragma unroll
        for (int q = 0; q < 2; ++q) {
            const int c = 2 * ps + q;
            F4H hu; hu.f4 = hb4[c];
            F4H wu; wu.f4 = wlf[c * 66 + pn];
            p = dot2(wu.h[0], hu.h[0], p);
            p = dot2(wu.h[1], hu.h[1], p);
            p = dot2(wu.h[2], hu.h[2], p);
            p = dot2(wu.h[3], hu.h[3], p);
        }
        p += __shfl_down(p, 4, 8);
        p += __shfl_down(p, 2, 8);
        p += __shfl_down(p, 1, 8);
        if (ps == 0) orow[t * OO + pn] = p + bl;
    }
}

extern "C" void kernel_launch(void* const* d_in, const int* in_sizes, int n_in,
                              void* d_out, int out_size, void* d_ws, size_t ws_size,
                              hipStream_t stream) {
    (void)in_sizes; (void)n_in; (void)d_ws; (void)ws_size; (void)out_size;
    const float* x      = (const float*)d_in[0];
    const float* Wx_out = (const float*)d_in[1];
    const float* Wh_out = (const float*)d_in[2];
    const float* b_out  = (const float*)d_in[3];
    const float* Wx_in  = (const float*)d_in[4];
    const float* Wh_in  = (const float*)d_in[5];
    const float* b_in   = (const float*)d_in[6];
    const float* W_lin  = (const float*)d_in[7];
    const float* b_lin  = (const float*)d_in[8];
    float* out = (float*)d_out;

    nlstm_scan<<<dim3(BB), dim3(512), 0, stream>>>(
        x, Wx_out, Wh_out, b_out, Wx_in, Wh_in, b_in, W_lin, b_lin, out);
}